// Round 6
// baseline (127.211 us; speedup 1.0000x reference)
//
#include <hip/hip_runtime.h>
#include <stdint.h>

// Croston's method: B=8192 series x T=2048 steps. out = Z'/V' per step.
//
// Round 17 = Round 16 with ONE change: non-temporal stores -> normal vf4
// stores. Evidence: R10-R16 varied staging mechanism (LDS-DMA depth 2/4,
// asm-hidden DS ops, reg-staged VGPR depth-3), wave count (4 vs 8 /CU),
// and vmcnt discipline -- croston pinned at 40-45us / ~2.8 TB/s in every
// variant. Reads are mostly L3-served (R12: FETCH 47.6MB < 92MB app-level).
// The component NEVER varied: __builtin_nontemporal_store. Mechanism:
// NT bypasses L2 + memory-side Infinity Cache -> each wave emits scattered
// 128B write chunks (64 rows x 8KB stride) straight at HBM: poor DRAM
// bank/page efficiency + read/write turnaround, and NT retire-at-HBM-ack
// (~1us) couples into every later vmcnt wait via in-order retirement.
// Normal stores ack at L2 and drain as large writeback bursts (the 6.3TB/s
// fill kernels use the normal path). Single-variable test of that theory.
// Kept from R16: reg-staged global->VGPR depth-3 prefetch, CH=128 (2048
// waves, 8/CU, all resident), 32KB LDS ring, XCD swizzle, R10-verified
// rotation transpose, WARM=128, exact c=0 state, no inline asm.

#define TLEN 2048
#define CH   128
#define WARM 128
#define TW   32                // tile = 64 rows x 32 steps = 8KB

typedef float vf4 __attribute__((ext_vector_type(4)));

__global__ __launch_bounds__(128) void croston_kernel(
    const float* __restrict__ x,
    const float* __restrict__ alpha,
    const float* __restrict__ Z0,
    const float* __restrict__ V0,
    const float* __restrict__ q0,
    float* __restrict__ out)
{
    __shared__ __attribute__((aligned(16))) float ring[2][2][64 * TW]; // 32KB

    const int warp = threadIdx.x >> 6;
    const int lane = threadIdx.x & 63;

    // XCD-locality swizzle (xcd = blockIdx % 8 heuristic; perf-only)
    const int xr = blockIdx.x & 7;
    const int bm = blockIdx.x >> 3;           // 0..127
    const int sg = xr * 16 + (bm & 15);       // series group pinned to XCD xr
    const int c  = (bm >> 4) * 2 + warp;      // chunk 0..15

    const int sbase = sg * 64;
    const int t_start = (c == 0) ? 0 : (c * CH - WARM);

    const float a  = alpha[0];
    const float ma = 1.0f - a;

    float Z, V, q;
    if (c == 0) {
        Z = Z0[sbase + lane];
        V = V0[sbase + lane];
        q = q0[sbase + lane];
    } else {
        Z = 1.0f; V = 1.0f; q = 1.0f;
    }

    const int rho = lane >> 3;               // row-in-octet (0..7)
    const int k8  = lane & 7;                // 16B chunk slot / rotation key
    const int mrot = ((k8 + rho) & 7) * 4;   // staging-side rotated time offset

    float* ring0 = ring[warp][0];
    float* ring1 = ring[warp][1];

    // Coalesced 16B loads, identical addresses to the old DMA.
    auto load_tile = [&](vf4* st, int t0) {
        const float* gbase = x + (size_t)(sbase + rho) * TLEN + t0 + mrot;
        #pragma unroll
        for (int i = 0; i < 8; ++i)
            st[i] = *(const vf4*)(gbase + (size_t)i * 8 * TLEN);
    };

    auto step = [&](float xt) {
        const bool  nz = (xt != 0.0f);
        const float Zn = fmaf(ma, Z, a * xt);
        const float Vn = fmaf(ma, V, a * q);
        Z = nz ? Zn : Z;
        V = nz ? Vn : V;
        q = nz ? 1.0f : q + 1.0f;
    };

    // One tile: stage VGPR->LDS (rotation layout), read rows, run the
    // recurrence; on emit, write outputs into the freed slot, read back
    // transposed, store coalesced through the NORMAL cache path.
    auto tile = [&](vf4* st, int T, bool emit) {
        float* slot = (T & 1) ? ring1 : ring0;
        const int t0 = t_start + T * TW;
        #pragma unroll
        for (int i = 0; i < 8; ++i)            // lane's 16B at byte l*16 (+1KB/i)
            *(vf4*)(slot + i * 256 + lane * 4) = st[i];
        vf4 v[8];
        #pragma unroll
        for (int mm = 0; mm < 8; ++mm)
            v[mm] = *(const vf4*)(slot + lane * 32 + (((mm - k8) & 7) << 2));
        if (emit) {
            #pragma unroll
            for (int mm = 0; mm < 8; ++mm) {
                #pragma unroll
                for (int k = 0; k < 4; ++k) {
                    step(v[mm][k]);
                    v[mm][k] = Z * __builtin_amdgcn_rcpf(V);
                }
            }
            #pragma unroll
            for (int mm = 0; mm < 8; ++mm)     // outputs into freed slot
                *(vf4*)(slot + lane * 32 + (((mm - k8) & 7) << 2)) = v[mm];
            #pragma unroll
            for (int i = 0; i < 8; ++i) {      // coalesced NORMAL stores
                const float* p = slot + (i * 8 + rho) * 32 + (((k8 - rho) & 7) << 2);
                vf4 o4; o4.x = p[0]; o4.y = p[1]; o4.z = p[2]; o4.w = p[3];
                *(vf4*)(out + (size_t)(sbase + i * 8 + rho) * TLEN + t0 + (k8 << 2)) = o4;
            }
        } else {
            #pragma unroll
            for (int mm = 0; mm < 8; ++mm) {
                #pragma unroll
                for (int k = 0; k < 4; ++k) step(v[mm][k]);
            }
        }
    };

    // Depth-3 register staging (named arrays: all indices compile-time).
    vf4 stA[8], stB[8], stC[8];
    load_tile(stA, t_start);
    load_tile(stB, t_start + TW);
    load_tile(stC, t_start + 2 * TW);

    if (c == 0) {
        // 4 emit tiles.
        tile(stA, 0, true);  load_tile(stA, t_start + 3 * TW);
        tile(stB, 1, true);
        tile(stC, 2, true);
        tile(stA, 3, true);
    } else {
        // 8 tiles: 0..3 warmup, 4..7 emit; refill 3 tiles ahead.
        tile(stA, 0, false); load_tile(stA, t_start + 3 * TW);
        tile(stB, 1, false); load_tile(stB, t_start + 4 * TW);
        tile(stC, 2, false); load_tile(stC, t_start + 5 * TW);
        tile(stA, 3, false); load_tile(stA, t_start + 6 * TW);
        tile(stB, 4, true);  load_tile(stB, t_start + 7 * TW);
        tile(stC, 5, true);
        tile(stA, 6, true);
        tile(stB, 7, true);
    }
}

extern "C" void kernel_launch(void* const* d_in, const int* in_sizes, int n_in,
                              void* d_out, int out_size, void* d_ws, size_t ws_size,
                              hipStream_t stream) {
    const float* x     = (const float*)d_in[0];
    const float* alpha = (const float*)d_in[1];
    const float* Z0    = (const float*)d_in[2];
    const float* V0    = (const float*)d_in[3];
    const float* q0    = (const float*)d_in[4];
    float* out = (float*)d_out;

    // 2048 waves = 128 sgs x 16 chunks, 2 independent waves/block,
    // block->XCD swizzled; 8 waves/CU (2/SIMD), all resident in one round.
    dim3 block(128);
    dim3 grid(1024);
    croston_kernel<<<grid, block, 0, stream>>>(x, alpha, Z0, V0, q0, out);
}